// Round 2
// baseline (376.768 us; speedup 1.0000x reference)
//
#include <hip/hip_runtime.h>
#include <hip/hip_bf16.h>

using bf16 = __hip_bfloat16;
typedef __attribute__((ext_vector_type(8))) __bf16 bf16x8;
typedef __attribute__((ext_vector_type(4))) float f32x4;

static constexpr int T = 4096, DIM = 768, H = 6, D = 128, N3 = 2304;
static constexpr float kEps = 1.1920929e-07f;
static constexpr float kScale = 0.12f;

__device__ __forceinline__ void gll16(const bf16* g, bf16* l) {
  __builtin_amdgcn_global_load_lds((const __attribute__((address_space(1))) void*)g,
                                   (__attribute__((address_space(3))) void*)l, 16, 0, 0);
}

// fp32 -> bf16, 8 elements/thread, n % 8 == 0
__global__ __launch_bounds__(256) void cvt(const float* __restrict__ in,
                                           bf16* __restrict__ out, int n) {
  const int i = (blockIdx.x * 256 + threadIdx.x) * 8;
  if (i >= n) return;
  const float4 a = *(const float4*)(in + i);
  const float4 b = *(const float4*)(in + i + 4);
  bf16 t[8] = {(bf16)a.x, (bf16)a.y, (bf16)a.z, (bf16)a.w,
               (bf16)b.x, (bf16)b.y, (bf16)b.z, (bf16)b.w};
  *(int4*)(out + i) = *(const int4*)t;
}

// C(MxN) = A(MxK) * B(NxK)^T, A/B row-major bf16, C row-major CT. M%128==0, N%128==0, K%64==0.
template <typename CT>
__global__ __launch_bounds__(256) void gemm_bt(const bf16* __restrict__ A,
                                               const bf16* __restrict__ B,
                                               CT* __restrict__ C,
                                               int M, int N, int K) {
  __shared__ bf16 lA[128][64];
  __shared__ bf16 lB[128][64];
  const int tid = threadIdx.x, lane = tid & 63, wid = tid >> 6;
  const int brow = blockIdx.y * 128, bcol = blockIdx.x * 128;
  const int wm = (wid >> 1) * 64, wn = (wid & 1) * 64;
  const int r = lane & 15, g = lane >> 4;
  f32x4 acc[4][4] = {};
  const int srow = wid * 32 + (lane >> 3);
  const int scol = (lane & 7) * 8;
  const bf16* gA = A + (long)(brow + srow) * K + scol;
  const bf16* gB = B + (long)(bcol + srow) * K + scol;
  for (int k0 = 0; k0 < K; k0 += 64) {
    __syncthreads();
#pragma unroll
    for (int i = 0; i < 4; ++i) {
      gll16(gA + (long)i * 8 * K + k0, &lA[wid * 32 + i * 8][0]);
      gll16(gB + (long)i * 8 * K + k0, &lB[wid * 32 + i * 8][0]);
    }
    __syncthreads();
#pragma unroll
    for (int kk = 0; kk < 2; ++kk) {
      bf16x8 af[4], bfr[4];
#pragma unroll
      for (int m = 0; m < 4; ++m)
        af[m] = *(const bf16x8*)&lA[wm + m * 16 + r][kk * 32 + g * 8];
#pragma unroll
      for (int n = 0; n < 4; ++n)
        bfr[n] = *(const bf16x8*)&lB[wn + n * 16 + r][kk * 32 + g * 8];
#pragma unroll
      for (int m = 0; m < 4; ++m)
#pragma unroll
        for (int n = 0; n < 4; ++n)
          acc[m][n] = __builtin_amdgcn_mfma_f32_16x16x32_bf16(af[m], bfr[n], acc[m][n], 0, 0, 0);
    }
  }
  const int crow = brow + wm + g * 4;
  const int ccol = bcol + wn + r;
#pragma unroll
  for (int m = 0; m < 4; ++m)
#pragma unroll
    for (int n = 0; n < 4; ++n)
#pragma unroll
      for (int q = 0; q < 4; ++q)
        C[(long)(crow + m * 16 + q) * N + ccol + n * 16] = (CT)acc[m][n][q];
}

// RMS-norm q/k, rotary, v = l0*v + l1*ve. One wave per (t,h); lane owns d=lane and d=lane+64.
// qkv is bf16 (GEMM1 output); ve/lam are fp32 inputs. Writes q,k as (h,t,d); v transposed (h,d,t).
__global__ __launch_bounds__(256) void qkv_post(const bf16* __restrict__ qkv,
                                                const float* __restrict__ ve,
                                                const float* __restrict__ lam,
                                                bf16* __restrict__ qb,
                                                bf16* __restrict__ kb,
                                                bf16* __restrict__ vt) {
  const int idx = blockIdx.x * 4 + (threadIdx.x >> 6);
  const int lane = threadIdx.x & 63;
  const int t = idx / H, h = idx % H;
  const bf16* row = qkv + (long)t * N3 + h * D;
  float q1 = __bfloat162float(row[lane]);
  float q2 = __bfloat162float(row[lane + 64]);
  float k1 = __bfloat162float(row[768 + lane]);
  float k2 = __bfloat162float(row[768 + lane + 64]);
  float v1 = __bfloat162float(row[1536 + lane]);
  float v2 = __bfloat162float(row[1536 + lane + 64]);
  float qs = q1 * q1 + q2 * q2, ks = k1 * k1 + k2 * k2;
#pragma unroll
  for (int off = 32; off; off >>= 1) {
    qs += __shfl_xor(qs, off);
    ks += __shfl_xor(ks, off);
  }
  const float qsc = rsqrtf(qs * (1.f / 128.f) + kEps);
  const float ksc = rsqrtf(ks * (1.f / 128.f) + kEps);
  q1 *= qsc; q2 *= qsc; k1 *= ksc; k2 *= ksc;
  float c = 1.f, s = 0.f;
  if (lane < 32) {
    const float af = exp2f(-10.f * (float)lane * (1.f / 31.f));
    sincosf((float)t * af, &s, &c);
  }
  const float nq1 = q1 * c + q2 * s, nq2 = q2 * c - q1 * s;
  const float nk1 = k1 * c + k2 * s, nk2 = k2 * c - k1 * s;
  const float l0 = lam[0], l1 = lam[1];
  const float* ver = ve + (long)t * DIM + h * D;
  v1 = l0 * v1 + l1 * ver[lane];
  v2 = l0 * v2 + l1 * ver[lane + 64];
  bf16* qo = qb + ((long)h * T + t) * D;
  bf16* ko = kb + ((long)h * T + t) * D;
  qo[lane] = (bf16)nq1; qo[lane + 64] = (bf16)nq2;
  ko[lane] = (bf16)nk1; ko[lane + 64] = (bf16)nk2;
  vt[((long)h * D + lane) * T + t] = (bf16)v1;
  vt[((long)h * D + lane + 64) * T + t] = (bf16)v2;
}

// Flash-style causal attention. Block: 64 q-rows (4 waves x 16), KV tiles of 32.
__global__ __launch_bounds__(256) void attn(const bf16* __restrict__ qb,
                                            const bf16* __restrict__ kb,
                                            const bf16* __restrict__ vt,
                                            bf16* __restrict__ yb) {
  __shared__ bf16 Kl[32][128];   // [s][d]
  __shared__ bf16 Vl[128][32];   // [d][s]  (V^T)
  __shared__ bf16 Pl[4][16][32]; // per-wave P bounce
  const int qblk = blockIdx.x, h = blockIdx.y;
  const int tid = threadIdx.x, lane = tid & 63, w = tid >> 6;
  const int r = lane & 15, g = lane >> 4;
  const int qrow0 = qblk * 64 + w * 16;
  const bf16* Q = qb + ((long)h * T + qrow0) * D;
  bf16x8 qf[4];
#pragma unroll
  for (int kk = 0; kk < 4; ++kk)
    qf[kk] = *(const bf16x8*)(Q + (long)r * D + kk * 32 + g * 8);
  f32x4 o[8] = {};
  float mrow[4] = {-1e30f, -1e30f, -1e30f, -1e30f};
  float srow[4] = {0.f, 0.f, 0.f, 0.f};
  const int kvend = qblk * 64 + 64;
  const bf16* Kg0 = kb + (long)h * T * D;
  const bf16* Vg0 = vt + (long)h * D * T;
  for (int kv0 = 0; kv0 < kvend; kv0 += 32) {
    __syncthreads();
#pragma unroll
    for (int j = 0; j < 2; ++j) {   // K tile: linear 8KB
      const int e = j * 2048 + w * 512;
      gll16(Kg0 + (long)kv0 * D + e + lane * 8, &Kl[0][0] + e);
    }
#pragma unroll
    for (int j = 0; j < 2; ++j) {   // V^T tile: rows of 32 from (h,d,t)
      const int e = j * 2048 + w * 512;
      const int el = e + lane * 8;
      gll16(Vg0 + (long)(el >> 5) * T + kv0 + (el & 31), &Vl[0][0] + e);
    }
    __syncthreads();
    if (kv0 > qrow0 + 15) continue;  // fully masked for this wave (barriers already done)
    f32x4 st[2];
#pragma unroll
    for (int tile = 0; tile < 2; ++tile) {
      f32x4 sacc = {};
#pragma unroll
      for (int kk = 0; kk < 4; ++kk) {
        bf16x8 kf = *(const bf16x8*)&Kl[tile * 16 + r][kk * 32 + g * 8];
        sacc = __builtin_amdgcn_mfma_f32_16x16x32_bf16(qf[kk], kf, sacc, 0, 0, 0);
      }
      st[tile] = sacc;
    }
    const int qg = qrow0 + 4 * g;
#pragma unroll
    for (int tile = 0; tile < 2; ++tile)
#pragma unroll
      for (int q = 0; q < 4; ++q) {
        const float sv = st[tile][q] * kScale;
        st[tile][q] = (kv0 + tile * 16 + r > qg + q) ? -1e30f : sv;
      }
    float mx[4];
#pragma unroll
    for (int q = 0; q < 4; ++q) mx[q] = fmaxf(st[0][q], st[1][q]);
#pragma unroll
    for (int off = 1; off < 16; off <<= 1)
#pragma unroll
      for (int q = 0; q < 4; ++q) mx[q] = fmaxf(mx[q], __shfl_xor(mx[q], off));
    float alpha[4];
#pragma unroll
    for (int q = 0; q < 4; ++q) {
      const float mn = fmaxf(mrow[q], mx[q]);
      alpha[q] = __expf(mrow[q] - mn);
      mrow[q] = mn;
    }
    float ps[4];
#pragma unroll
    for (int q = 0; q < 4; ++q) {
      st[0][q] = __expf(st[0][q] - mrow[q]);
      st[1][q] = __expf(st[1][q] - mrow[q]);
      ps[q] = st[0][q] + st[1][q];
    }
#pragma unroll
    for (int off = 1; off < 16; off <<= 1)
#pragma unroll
      for (int q = 0; q < 4; ++q) ps[q] += __shfl_xor(ps[q], off);
#pragma unroll
    for (int q = 0; q < 4; ++q) srow[q] = srow[q] * alpha[q] + ps[q];
#pragma unroll
    for (int n = 0; n < 8; ++n)
#pragma unroll
      for (int q = 0; q < 4; ++q) o[n][q] *= alpha[q];
#pragma unroll
    for (int tile = 0; tile < 2; ++tile)
#pragma unroll
      for (int q = 0; q < 4; ++q)
        Pl[w][4 * g + q][tile * 16 + r] = (bf16)st[tile][q];
    const bf16x8 pf = *(const bf16x8*)&Pl[w][r][g * 8];
#pragma unroll
    for (int n = 0; n < 8; ++n) {
      bf16x8 vf = *(const bf16x8*)&Vl[n * 16 + r][g * 8];
      o[n] = __builtin_amdgcn_mfma_f32_16x16x32_bf16(pf, vf, o[n], 0, 0, 0);
    }
  }
#pragma unroll
  for (int n = 0; n < 8; ++n)
#pragma unroll
    for (int q = 0; q < 4; ++q)
      yb[(long)(qrow0 + 4 * g + q) * DIM + h * D + n * 16 + r] = (bf16)(o[n][q] / srow[q]);
}

extern "C" void kernel_launch(void* const* d_in, const int* in_sizes, int n_in,
                              void* d_out, int out_size, void* d_ws, size_t ws_size,
                              hipStream_t stream) {
  const float* x     = (const float*)d_in[0];
  const float* ve    = (const float*)d_in[1];
  const float* qkv_w = (const float*)d_in[2];
  const float* lam   = (const float*)d_in[3];
  const float* cproj = (const float*)d_in[4];
  float* out = (float*)d_out;

  bf16* xb  = (bf16*)d_ws;                 // T*DIM
  bf16* wb  = xb + (long)T * DIM;          // N3*DIM
  bf16* cb  = wb + (long)N3 * DIM;         // DIM*DIM
  bf16* qkv = cb + (long)DIM * DIM;        // T*N3
  bf16* qb  = qkv + (long)T * N3;          // H*T*D
  bf16* kb  = qb + (long)H * T * D;
  bf16* vt  = kb + (long)H * T * D;        // (h, d, t)
  bf16* yb  = vt + (long)H * T * D;        // T*DIM

  cvt<<<dim3(T * DIM / 8 / 256), 256, 0, stream>>>(x, xb, T * DIM);
  cvt<<<dim3(N3 * DIM / 8 / 256), 256, 0, stream>>>(qkv_w, wb, N3 * DIM);
  cvt<<<dim3(DIM * DIM / 8 / 256), 256, 0, stream>>>(cproj, cb, DIM * DIM);

  gemm_bt<bf16><<<dim3(N3 / 128, T / 128), 256, 0, stream>>>(xb, wb, qkv, T, N3, DIM);
  qkv_post<<<dim3(T * H / 4), 256, 0, stream>>>(qkv, ve, lam, qb, kb, vt);
  attn<<<dim3(T / 64, H), 256, 0, stream>>>(qb, kb, vt, yb);
  gemm_bt<float><<<dim3(DIM / 128, T / 128), 256, 0, stream>>>(yb, cb, out, T, DIM, DIM);
}

// Round 3
// 233.728 us; speedup vs baseline: 1.6120x; 1.6120x over previous
//
#include <hip/hip_runtime.h>
#include <hip/hip_bf16.h>

using bf16 = __hip_bfloat16;
typedef __attribute__((ext_vector_type(8))) __bf16 bf16x8;
typedef __attribute__((ext_vector_type(4))) float f32x4;

static constexpr int T = 4096, DIM = 768, H = 6, D = 128, N3 = 2304;
static constexpr float kEps = 1.1920929e-07f;
static constexpr float kScale = 0.12f;

__device__ __forceinline__ void gll16(const bf16* g, bf16* l) {
  __builtin_amdgcn_global_load_lds((const __attribute__((address_space(1))) void*)g,
                                   (__attribute__((address_space(3))) void*)l, 16, 0, 0);
}

// fp32 -> bf16, 8 elements/thread, n % 8 == 0
__global__ __launch_bounds__(256) void cvt(const float* __restrict__ in,
                                           bf16* __restrict__ out, int n) {
  const int i = (blockIdx.x * 256 + threadIdx.x) * 8;
  if (i >= n) return;
  const float4 a = *(const float4*)(in + i);
  const float4 b = *(const float4*)(in + i + 4);
  bf16 t[8] = {(bf16)a.x, (bf16)a.y, (bf16)a.z, (bf16)a.w,
               (bf16)b.x, (bf16)b.y, (bf16)b.z, (bf16)b.w};
  *(int4*)(out + i) = *(const int4*)t;
}

// C(MxN) = A(MxK) * B(NxK)^T, A/B row-major bf16, C row-major CT.
template <typename CT>
__global__ __launch_bounds__(256) void gemm_bt(const bf16* __restrict__ A,
                                               const bf16* __restrict__ B,
                                               CT* __restrict__ C,
                                               int M, int N, int K) {
  __shared__ bf16 lA[128][64];
  __shared__ bf16 lB[128][64];
  const int tid = threadIdx.x, lane = tid & 63, wid = tid >> 6;
  const int brow = blockIdx.y * 128, bcol = blockIdx.x * 128;
  const int wm = (wid >> 1) * 64, wn = (wid & 1) * 64;
  const int r = lane & 15, g = lane >> 4;
  f32x4 acc[4][4] = {};
  const int srow = wid * 32 + (lane >> 3);
  const int scol = (lane & 7) * 8;
  const bf16* gA = A + (long)(brow + srow) * K + scol;
  const bf16* gB = B + (long)(bcol + srow) * K + scol;
  for (int k0 = 0; k0 < K; k0 += 64) {
    __syncthreads();
#pragma unroll
    for (int i = 0; i < 4; ++i) {
      gll16(gA + (long)i * 8 * K + k0, &lA[wid * 32 + i * 8][0]);
      gll16(gB + (long)i * 8 * K + k0, &lB[wid * 32 + i * 8][0]);
    }
    __syncthreads();
#pragma unroll
    for (int kk = 0; kk < 2; ++kk) {
      bf16x8 af[4], bfr[4];
#pragma unroll
      for (int m = 0; m < 4; ++m)
        af[m] = *(const bf16x8*)&lA[wm + m * 16 + r][kk * 32 + g * 8];
#pragma unroll
      for (int n = 0; n < 4; ++n)
        bfr[n] = *(const bf16x8*)&lB[wn + n * 16 + r][kk * 32 + g * 8];
#pragma unroll
      for (int m = 0; m < 4; ++m)
#pragma unroll
        for (int n = 0; n < 4; ++n)
          acc[m][n] = __builtin_amdgcn_mfma_f32_16x16x32_bf16(af[m], bfr[n], acc[m][n], 0, 0, 0);
    }
  }
  const int crow = brow + wm + g * 4;
  const int ccol = bcol + wn + r;
#pragma unroll
  for (int m = 0; m < 4; ++m)
#pragma unroll
    for (int n = 0; n < 4; ++n)
#pragma unroll
      for (int q = 0; q < 4; ++q)
        C[(long)(crow + m * 16 + q) * N + ccol + n * 16] = (CT)acc[m][n][q];
}

// RMS-norm + rotary for q,k only. One wave per (t,h). Writes (h,t,d).
__global__ __launch_bounds__(256) void qkv_post(const bf16* __restrict__ qkv,
                                                bf16* __restrict__ qb,
                                                bf16* __restrict__ kb) {
  const int idx = blockIdx.x * 4 + (threadIdx.x >> 6);
  const int lane = threadIdx.x & 63;
  const int t = idx / H, h = idx % H;
  const bf16* row = qkv + (long)t * N3 + h * D;
  float q1 = __bfloat162float(row[lane]);
  float q2 = __bfloat162float(row[lane + 64]);
  float k1 = __bfloat162float(row[768 + lane]);
  float k2 = __bfloat162float(row[768 + lane + 64]);
  float qs = q1 * q1 + q2 * q2, ks = k1 * k1 + k2 * k2;
#pragma unroll
  for (int off = 32; off; off >>= 1) {
    qs += __shfl_xor(qs, off);
    ks += __shfl_xor(ks, off);
  }
  const float qsc = rsqrtf(qs * (1.f / 128.f) + kEps);
  const float ksc = rsqrtf(ks * (1.f / 128.f) + kEps);
  q1 *= qsc; q2 *= qsc; k1 *= ksc; k2 *= ksc;
  float c = 1.f, s = 0.f;
  if (lane < 32) {
    const float af = exp2f(-10.f * (float)lane * (1.f / 31.f));
    sincosf((float)t * af, &s, &c);
  }
  const float nq1 = q1 * c + q2 * s, nq2 = q2 * c - q1 * s;
  const float nk1 = k1 * c + k2 * s, nk2 = k2 * c - k1 * s;
  bf16* qo = qb + ((long)h * T + t) * D;
  bf16* ko = kb + ((long)h * T + t) * D;
  qo[lane] = (bf16)nq1; qo[lane + 64] = (bf16)nq2;
  ko[lane] = (bf16)nk1; ko[lane + 64] = (bf16)nk2;
}

// v = l0*v + l1*ve, transposed to (h, d, t) with coalesced 64B stores.
__global__ __launch_bounds__(256) void v_trans(const bf16* __restrict__ qkv,
                                               const float* __restrict__ ve,
                                               const float* __restrict__ lam,
                                               bf16* __restrict__ vt) {
  __shared__ bf16 tile[64][129];
  const int t0 = blockIdx.x * 64, h = blockIdx.y;
  const int tid = threadIdx.x;
  const float l0 = lam[0], l1 = lam[1];
  const int row = tid >> 2;
  const int seg = (tid & 3) * 32;
  const bf16* src = qkv + (long)(t0 + row) * N3 + 1536 + h * D + seg;
  const float* vs = ve + (long)(t0 + row) * DIM + h * D + seg;
#pragma unroll
  for (int j = 0; j < 32; j += 8) {
    bf16x8 a = *(const bf16x8*)(src + j);
    const float4 e0 = *(const float4*)(vs + j);
    const float4 e1 = *(const float4*)(vs + j + 4);
    const float ef[8] = {e0.x, e0.y, e0.z, e0.w, e1.x, e1.y, e1.z, e1.w};
#pragma unroll
    for (int u = 0; u < 8; ++u)
      tile[row][seg + j + u] = (bf16)(l0 * (float)a[u] + l1 * ef[u]);
  }
  __syncthreads();
  const int d = tid >> 1, half = tid & 1;
  bf16 outr[32];
#pragma unroll
  for (int j = 0; j < 32; ++j) outr[j] = tile[half * 32 + j][d];
  bf16* dst = vt + ((long)h * D + d) * T + t0 + half * 32;
#pragma unroll
  for (int c = 0; c < 4; ++c)
    *(int4*)(dst + c * 8) = *(const int4*)&outr[c * 8];
}

// Flash-style causal attention. Block b handles q-tiles {b, 63-b} (64 rows each,
// 4 waves x 16 rows) against a shared KV stream, KVBLK=64, double-buffered LDS,
// XOR chunk-swizzle (chunk ^= row&7) on K/V/P.
__global__ __launch_bounds__(256, 1) void attn(const bf16* __restrict__ qb,
                                               const bf16* __restrict__ kb,
                                               const bf16* __restrict__ vt,
                                               bf16* __restrict__ yb) {
  __shared__ bf16 Kl[2][64][128];
  __shared__ bf16 Vl[2][128][64];
  __shared__ bf16 Pl[4][2][16][64];
  const int b = blockIdx.x, h = blockIdx.y;
  const int tid = threadIdx.x, lane = tid & 63, w = tid >> 6;
  const int r = lane & 15, g = lane >> 4;
  const int q1t = b, q2t = 63 - b;
  const int nt = 64 - b;
  const int q1row = q1t * 64 + w * 16, q2row = q2t * 64 + w * 16;

  bf16x8 qf1[4], qf2[4];
#pragma unroll
  for (int kk = 0; kk < 4; ++kk) {
    qf1[kk] = *(const bf16x8*)(qb + ((long)h * T + q1row + r) * D + kk * 32 + g * 8);
    qf2[kk] = *(const bf16x8*)(qb + ((long)h * T + q2row + r) * D + kk * 32 + g * 8);
  }
  f32x4 o1[8] = {}, o2[8] = {};
  float m1[4], s1[4], m2[4], s2[4];
#pragma unroll
  for (int q = 0; q < 4; ++q) { m1[q] = -1e30f; s1[q] = 0.f; m2[q] = -1e30f; s2[q] = 0.f; }

  auto STAGE = [&](int buf, int t) {
    const int kv0 = t * 64;
#pragma unroll
    for (int i = 0; i < 4; ++i) {
      const int seg = w * 4 + i;
      {
        const int lr = seg * 4 + (lane >> 4);
        const int cs = (lane & 15) ^ (lr & 7);
        gll16(kb + ((long)h * T + kv0 + lr) * D + cs * 8,
              (bf16*)&Kl[buf][0][0] + seg * 512);
      }
      {
        const int lr = seg * 8 + (lane >> 3);
        const int cs = (lane & 7) ^ (lr & 7);
        gll16(vt + ((long)h * D + lr) * T + kv0 + cs * 8,
              (bf16*)&Vl[buf][0][0] + seg * 512);
      }
    }
  };

  // softmax update + swizzled P write. st4 is raw QK^T accumulator.
  auto smup = [&](f32x4 (&st4)[4], float* m, float* s, f32x4 (&o)[8],
                  bf16* Pb, bool diag) {
#pragma unroll
    for (int stt = 0; stt < 4; ++stt)
#pragma unroll
      for (int q = 0; q < 4; ++q) st4[stt][q] *= kScale;
    if (diag) {
#pragma unroll
      for (int stt = 0; stt < 4; ++stt)
#pragma unroll
        for (int q = 0; q < 4; ++q)
          if (stt * 16 + r > w * 16 + 4 * g + q) st4[stt][q] = -1e30f;
    }
    float mx[4], al[4], ps[4];
#pragma unroll
    for (int q = 0; q < 4; ++q)
      mx[q] = fmaxf(fmaxf(st4[0][q], st4[1][q]), fmaxf(st4[2][q], st4[3][q]));
#pragma unroll
    for (int off = 1; off < 16; off <<= 1)
#pragma unroll
      for (int q = 0; q < 4; ++q) mx[q] = fmaxf(mx[q], __shfl_xor(mx[q], off));
#pragma unroll
    for (int q = 0; q < 4; ++q) {
      const float mn = fmaxf(m[q], mx[q]);
      al[q] = __expf(m[q] - mn);
      m[q] = mn;
    }
#pragma unroll
    for (int stt = 0; stt < 4; ++stt)
#pragma unroll
      for (int q = 0; q < 4; ++q) st4[stt][q] = __expf(st4[stt][q] - m[q]);
#pragma unroll
    for (int q = 0; q < 4; ++q)
      ps[q] = (st4[0][q] + st4[1][q]) + (st4[2][q] + st4[3][q]);
#pragma unroll
    for (int off = 1; off < 16; off <<= 1)
#pragma unroll
      for (int q = 0; q < 4; ++q) ps[q] += __shfl_xor(ps[q], off);
#pragma unroll
    for (int q = 0; q < 4; ++q) s[q] = s[q] * al[q] + ps[q];
#pragma unroll
    for (int n = 0; n < 8; ++n)
#pragma unroll
      for (int q = 0; q < 4; ++q) o[n][q] *= al[q];
#pragma unroll
    for (int stt = 0; stt < 4; ++stt)
#pragma unroll
      for (int q = 0; q < 4; ++q) {
        const int rw = 4 * g + q;
        Pb[rw * 64 + ((stt * 16 + r) ^ ((rw & 7) << 3))] = (bf16)st4[stt][q];
      }
  };

  STAGE(0, 0);
  __syncthreads();
  int cur = 0;
  for (int t = 0; t < nt; ++t) {
    if (t + 1 < nt) STAGE(cur ^ 1, t + 1);
    const bf16* Kb = (const bf16*)&Kl[cur][0][0];
    const bf16* Vb = (const bf16*)&Vl[cur][0][0];
    bf16* P1 = &Pl[w][0][0][0];
    bf16* P2 = &Pl[w][1][0][0];
    if (t <= b) {
      // both q-tiles active: share K/V fragment reads
      f32x4 s1t[4], s2t[4];
      __builtin_amdgcn_s_setprio(1);
#pragma unroll
      for (int stt = 0; stt < 4; ++stt) {
        f32x4 a1 = {}, a2 = {};
        const int lrk = stt * 16 + r;
#pragma unroll
        for (int kk = 0; kk < 4; ++kk) {
          const bf16x8 kf = *(const bf16x8*)(Kb + lrk * 128 + (((kk * 4 + g) ^ (r & 7)) * 8));
          a1 = __builtin_amdgcn_mfma_f32_16x16x32_bf16(qf1[kk], kf, a1, 0, 0, 0);
          a2 = __builtin_amdgcn_mfma_f32_16x16x32_bf16(qf2[kk], kf, a2, 0, 0, 0);
        }
        s1t[stt] = a1; s2t[stt] = a2;
      }
      __builtin_amdgcn_s_setprio(0);
      smup(s1t, m1, s1, o1, P1, t == b);
      smup(s2t, m2, s2, o2, P2, false);
      bf16x8 pf1[2], pf2[2];
#pragma unroll
      for (int kk = 0; kk < 2; ++kk) {
        pf1[kk] = *(const bf16x8*)(P1 + r * 64 + (((kk * 4 + g) ^ (r & 7)) * 8));
        pf2[kk] = *(const bf16x8*)(P2 + r * 64 + (((kk * 4 + g) ^ (r & 7)) * 8));
      }
      __builtin_amdgcn_s_setprio(1);
#pragma unroll
      for (int n = 0; n < 8; ++n) {
        const int d = n * 16 + r;
#pragma unroll
        for (int kk = 0; kk < 2; ++kk) {
          const bf16x8 vf = *(const bf16x8*)(Vb + d * 64 + (((kk * 4 + g) ^ (r & 7)) * 8));
          o1[n] = __builtin_amdgcn_mfma_f32_16x16x32_bf16(pf1[kk], vf, o1[n], 0, 0, 0);
          o2[n] = __builtin_amdgcn_mfma_f32_16x16x32_bf16(pf2[kk], vf, o2[n], 0, 0, 0);
        }
      }
      __builtin_amdgcn_s_setprio(0);
    } else {
      // only q2 active
      f32x4 s2t[4];
      __builtin_amdgcn_s_setprio(1);
#pragma unroll
      for (int stt = 0; stt < 4; ++stt) {
        f32x4 a2 = {};
        const int lrk = stt * 16 + r;
#pragma unroll
        for (int kk = 0; kk < 4; ++kk) {
          const bf16x8 kf = *(const bf16x8*)(Kb + lrk * 128 + (((kk * 4 + g) ^ (r & 7)) * 8));
          a2 = __builtin_amdgcn_mfma_f32_16x16x32_bf16(qf2[kk], kf, a2, 0, 0, 0);
        }
        s2t[stt] = a2;
      }
      __builtin_amdgcn_s_setprio(0);
      smup(s2t, m2, s2, o2, P2, t == nt - 1);
      bf16x8 pf2[2];
#pragma unroll
      for (int kk = 0; kk < 2; ++kk)
        pf2[kk] = *(const bf16x8*)(P2 + r * 64 + (((kk * 4 + g) ^ (r & 7)) * 8));
      __builtin_amdgcn_s_setprio(1);
#pragma unroll
      for (int n = 0; n < 8; ++n) {
        const int d = n * 16 + r;
#pragma unroll
        for (int kk = 0; kk < 2; ++kk) {
          const bf16x8 vf = *(const bf16x8*)(Vb + d * 64 + (((kk * 4 + g) ^ (r & 7)) * 8));
          o2[n] = __builtin_amdgcn_mfma_f32_16x16x32_bf16(pf2[kk], vf, o2[n], 0, 0, 0);
        }
      }
      __builtin_amdgcn_s_setprio(0);
    }
    __syncthreads();
    cur ^= 1;
  }
#pragma unroll
  for (int n = 0; n < 8; ++n)
#pragma unroll
    for (int q = 0; q < 4; ++q) {
      yb[(long)(q1t * 64 + w * 16 + 4 * g + q) * DIM + h * D + n * 16 + r] = (bf16)(o1[n][q] / s1[q]);
      yb[(long)(q2t * 64 + w * 16 + 4 * g + q) * DIM + h * D + n * 16 + r] = (bf16)(o2[n][q] / s2[q]);
    }
}

extern "C" void kernel_launch(void* const* d_in, const int* in_sizes, int n_in,
                              void* d_out, int out_size, void* d_ws, size_t ws_size,
                              hipStream_t stream) {
  const float* x     = (const float*)d_in[0];
  const float* ve    = (const float*)d_in[1];
  const float* qkv_w = (const float*)d_in[2];
  const float* lam   = (const float*)d_in[3];
  const float* cproj = (const float*)d_in[4];
  float* out = (float*)d_out;

  bf16* xb  = (bf16*)d_ws;                 // T*DIM
  bf16* wb  = xb + (long)T * DIM;          // N3*DIM
  bf16* cb  = wb + (long)N3 * DIM;         // DIM*DIM
  bf16* qkv = cb + (long)DIM * DIM;        // T*N3
  bf16* qb  = qkv + (long)T * N3;          // H*T*D
  bf16* kb  = qb + (long)H * T * D;
  bf16* vt  = kb + (long)H * T * D;        // (h, d, t)
  bf16* yb  = vt + (long)H * T * D;        // T*DIM

  cvt<<<dim3(T * DIM / 8 / 256), 256, 0, stream>>>(x, xb, T * DIM);
  cvt<<<dim3(N3 * DIM / 8 / 256), 256, 0, stream>>>(qkv_w, wb, N3 * DIM);
  cvt<<<dim3(DIM * DIM / 8 / 256), 256, 0, stream>>>(cproj, cb, DIM * DIM);

  gemm_bt<bf16><<<dim3(N3 / 128, T / 128), 256, 0, stream>>>(xb, wb, qkv, T, N3, DIM);
  qkv_post<<<dim3(T * H / 4), 256, 0, stream>>>(qkv, qb, kb);
  v_trans<<<dim3(T / 64, H), 256, 0, stream>>>(qkv, ve, lam, vt);
  attn<<<dim3(32, H), 256, 0, stream>>>(qb, kb, vt, yb);
  gemm_bt<float><<<dim3(DIM / 128, T / 128), 256, 0, stream>>>(yb, cb, out, T, DIM, DIM);
}

// Round 4
// 171.888 us; speedup vs baseline: 2.1919x; 1.3598x over previous
//
#include <hip/hip_runtime.h>
#include <hip/hip_bf16.h>

using bf16 = __hip_bfloat16;
typedef __attribute__((ext_vector_type(8))) __bf16 bf16x8;
typedef __attribute__((ext_vector_type(4))) float f32x4;

static constexpr int T = 4096, DIM = 768, H = 6, D = 128, N3 = 2304;
static constexpr int NPART = H * 64 * 2;
static constexpr float kEps = 1.1920929e-07f;
static constexpr float kScale = 0.12f;

__device__ __forceinline__ void gll16(const bf16* g, bf16* l) {
  __builtin_amdgcn_global_load_lds((const __attribute__((address_space(1))) void*)g,
                                   (__attribute__((address_space(3))) void*)l, 16, 0, 0);
}

// fp32 -> bf16, 8 elements/thread, n % 8 == 0
__global__ __launch_bounds__(256) void cvt(const float* __restrict__ in,
                                           bf16* __restrict__ out, int n) {
  const int i = (blockIdx.x * 256 + threadIdx.x) * 8;
  if (i >= n) return;
  const float4 a = *(const float4*)(in + i);
  const float4 b = *(const float4*)(in + i + 4);
  bf16 t[8] = {(bf16)a.x, (bf16)a.y, (bf16)a.z, (bf16)a.w,
               (bf16)b.x, (bf16)b.y, (bf16)b.z, (bf16)b.w};
  *(int4*)(out + i) = *(const int4*)t;
}

// C(MxN) = A(MxK) * B(NxK)^T, A/B row-major bf16, C row-major CT.
template <typename CT>
__global__ __launch_bounds__(256) void gemm_bt(const bf16* __restrict__ A,
                                               const bf16* __restrict__ B,
                                               CT* __restrict__ C,
                                               int M, int N, int K) {
  __shared__ bf16 lA[128][64];
  __shared__ bf16 lB[128][64];
  const int tid = threadIdx.x, lane = tid & 63, wid = tid >> 6;
  const int brow = blockIdx.y * 128, bcol = blockIdx.x * 128;
  const int wm = (wid >> 1) * 64, wn = (wid & 1) * 64;
  const int r = lane & 15, g = lane >> 4;
  f32x4 acc[4][4] = {};
  const int srow = wid * 32 + (lane >> 3);
  const int scol = (lane & 7) * 8;
  const bf16* gA = A + (long)(brow + srow) * K + scol;
  const bf16* gB = B + (long)(bcol + srow) * K + scol;
  for (int k0 = 0; k0 < K; k0 += 64) {
    __syncthreads();
#pragma unroll
    for (int i = 0; i < 4; ++i) {
      gll16(gA + (long)i * 8 * K + k0, &lA[wid * 32 + i * 8][0]);
      gll16(gB + (long)i * 8 * K + k0, &lB[wid * 32 + i * 8][0]);
    }
    __syncthreads();
#pragma unroll
    for (int kk = 0; kk < 2; ++kk) {
      bf16x8 af[4], bfr[4];
#pragma unroll
      for (int m = 0; m < 4; ++m)
        af[m] = *(const bf16x8*)&lA[wm + m * 16 + r][kk * 32 + g * 8];
#pragma unroll
      for (int n = 0; n < 4; ++n)
        bfr[n] = *(const bf16x8*)&lB[wn + n * 16 + r][kk * 32 + g * 8];
#pragma unroll
      for (int m = 0; m < 4; ++m)
#pragma unroll
        for (int n = 0; n < 4; ++n)
          acc[m][n] = __builtin_amdgcn_mfma_f32_16x16x32_bf16(af[m], bfr[n], acc[m][n], 0, 0, 0);
    }
  }
  const int crow = brow + wm + g * 4;
  const int ccol = bcol + wn + r;
#pragma unroll
  for (int m = 0; m < 4; ++m)
#pragma unroll
    for (int n = 0; n < 4; ++n)
#pragma unroll
      for (int q = 0; q < 4; ++q)
        C[(long)(crow + m * 16 + q) * N + ccol + n * 16] = (CT)acc[m][n][q];
}

// RMS-norm + rotary for q,k only. One wave per (t,h). Writes (h,t,d).
__global__ __launch_bounds__(256) void qkv_post(const bf16* __restrict__ qkv,
                                                bf16* __restrict__ qb,
                                                bf16* __restrict__ kb) {
  const int idx = blockIdx.x * 4 + (threadIdx.x >> 6);
  const int lane = threadIdx.x & 63;
  const int t = idx / H, h = idx % H;
  const bf16* row = qkv + (long)t * N3 + h * D;
  float q1 = __bfloat162float(row[lane]);
  float q2 = __bfloat162float(row[lane + 64]);
  float k1 = __bfloat162float(row[768 + lane]);
  float k2 = __bfloat162float(row[768 + lane + 64]);
  float qs = q1 * q1 + q2 * q2, ks = k1 * k1 + k2 * k2;
#pragma unroll
  for (int off = 32; off; off >>= 1) {
    qs += __shfl_xor(qs, off);
    ks += __shfl_xor(ks, off);
  }
  const float qsc = rsqrtf(qs * (1.f / 128.f) + kEps);
  const float ksc = rsqrtf(ks * (1.f / 128.f) + kEps);
  q1 *= qsc; q2 *= qsc; k1 *= ksc; k2 *= ksc;
  float c = 1.f, s = 0.f;
  if (lane < 32) {
    const float af = exp2f(-10.f * (float)lane * (1.f / 31.f));
    sincosf((float)t * af, &s, &c);
  }
  const float nq1 = q1 * c + q2 * s, nq2 = q2 * c - q1 * s;
  const float nk1 = k1 * c + k2 * s, nk2 = k2 * c - k1 * s;
  bf16* qo = qb + ((long)h * T + t) * D;
  bf16* ko = kb + ((long)h * T + t) * D;
  qo[lane] = (bf16)nq1; qo[lane + 64] = (bf16)nq2;
  ko[lane] = (bf16)nk1; ko[lane + 64] = (bf16)nk2;
}

// v = l0*v + l1*ve, transposed to (h, d, t) with coalesced 64B stores.
__global__ __launch_bounds__(256) void v_trans(const bf16* __restrict__ qkv,
                                               const float* __restrict__ ve,
                                               const float* __restrict__ lam,
                                               bf16* __restrict__ vt) {
  __shared__ bf16 tile[64][129];
  const int t0 = blockIdx.x * 64, h = blockIdx.y;
  const int tid = threadIdx.x;
  const float l0 = lam[0], l1 = lam[1];
  const int row = tid >> 2;
  const int seg = (tid & 3) * 32;
  const bf16* src = qkv + (long)(t0 + row) * N3 + 1536 + h * D + seg;
  const float* vs = ve + (long)(t0 + row) * DIM + h * D + seg;
#pragma unroll
  for (int j = 0; j < 32; j += 8) {
    bf16x8 a = *(const bf16x8*)(src + j);
    const float4 e0 = *(const float4*)(vs + j);
    const float4 e1 = *(const float4*)(vs + j + 4);
    const float ef[8] = {e0.x, e0.y, e0.z, e0.w, e1.x, e1.y, e1.z, e1.w};
#pragma unroll
    for (int u = 0; u < 8; ++u)
      tile[row][seg + j + u] = (bf16)(l0 * (float)a[u] + l1 * ef[u]);
  }
  __syncthreads();
  const int d = tid >> 1, half = tid & 1;
  bf16 outr[32];
#pragma unroll
  for (int j = 0; j < 32; ++j) outr[j] = tile[half * 32 + j][d];
  bf16* dst = vt + ((long)h * D + d) * T + t0 + half * 32;
#pragma unroll
  for (int c = 0; c < 4; ++c)
    *(int4*)(dst + c * 8) = *(const int4*)&outr[c * 8];
}

// Flash-style causal attention, KV-split (2 chunks per q-tile).
// Block bid: cr = bid/H heavy-first -> qt = 63 - (cr>>1), chunk c = cr&1.
// 64 q-rows (4 waves x 16), KVBLK=64, double-buffered LDS, XOR chunk-swizzle.
// Writes partial (o, m, s) for later merge.
__global__ __launch_bounds__(256, 2) void attn(const bf16* __restrict__ qb,
                                               const bf16* __restrict__ kb,
                                               const bf16* __restrict__ vt,
                                               float* __restrict__ po,
                                               float* __restrict__ pm,
                                               float* __restrict__ ps) {
  __shared__ bf16 Kl[2][64][128];
  __shared__ bf16 Vl[2][128][64];
  __shared__ bf16 Pl[4][16][64];
  const int bid = blockIdx.x;
  const int cr = bid / H, h = bid % H;
  const int qt = 63 - (cr >> 1), c = cr & 1;
  const int n = qt + 1, half = n >> 1;
  const int ts = c ? half : 0;
  const int te = c ? n : half;
  const int tid = threadIdx.x, lane = tid & 63, w = tid >> 6;
  const int r = lane & 15, g = lane >> 4;
  const int qrow = qt * 64 + w * 16;

  bf16x8 qf[4];
#pragma unroll
  for (int kk = 0; kk < 4; ++kk)
    qf[kk] = *(const bf16x8*)(qb + ((long)h * T + qrow + r) * D + kk * 32 + g * 8);
  f32x4 o[8] = {};
  float m[4], s[4];
#pragma unroll
  for (int q = 0; q < 4; ++q) { m[q] = -1e30f; s[q] = 0.f; }

  auto STAGE = [&](int buf, int t) {
    const int kv0 = t * 64;
#pragma unroll
    for (int i = 0; i < 4; ++i) {
      const int seg = w * 4 + i;
      {
        const int lr = seg * 4 + (lane >> 4);
        const int cs = (lane & 15) ^ (lr & 7);
        gll16(kb + ((long)h * T + kv0 + lr) * D + cs * 8,
              (bf16*)&Kl[buf][0][0] + seg * 512);
      }
      {
        const int lr = seg * 8 + (lane >> 3);
        const int cs = (lane & 7) ^ (lr & 7);
        gll16(vt + ((long)h * D + lr) * T + kv0 + cs * 8,
              (bf16*)&Vl[buf][0][0] + seg * 512);
      }
    }
  };

  if (te > ts) {
    STAGE(0, ts);
    __syncthreads();
    int cur = 0;
    for (int t = ts; t < te; ++t) {
      if (t + 1 < te) STAGE(cur ^ 1, t + 1);
      const bf16* Kb = (const bf16*)&Kl[cur][0][0];
      const bf16* Vb = (const bf16*)&Vl[cur][0][0];
      bf16* Pb = &Pl[w][0][0];
      f32x4 st4[4];
      __builtin_amdgcn_s_setprio(1);
#pragma unroll
      for (int stt = 0; stt < 4; ++stt) {
        f32x4 a = {};
        const int lrk = stt * 16 + r;
#pragma unroll
        for (int kk = 0; kk < 4; ++kk) {
          const bf16x8 kf = *(const bf16x8*)(Kb + lrk * 128 + (((kk * 4 + g) ^ (r & 7)) * 8));
          a = __builtin_amdgcn_mfma_f32_16x16x32_bf16(qf[kk], kf, a, 0, 0, 0);
        }
        st4[stt] = a;
      }
      __builtin_amdgcn_s_setprio(0);
      // softmax update with defer-max (THR=8)
#pragma unroll
      for (int stt = 0; stt < 4; ++stt)
#pragma unroll
        for (int q = 0; q < 4; ++q) st4[stt][q] *= kScale;
      if (t == qt) {
#pragma unroll
        for (int stt = 0; stt < 4; ++stt)
#pragma unroll
          for (int q = 0; q < 4; ++q)
            if (stt * 16 + r > w * 16 + 4 * g + q) st4[stt][q] = -1e30f;
      }
      float mx[4], al[4], ps4[4];
#pragma unroll
      for (int q = 0; q < 4; ++q)
        mx[q] = fmaxf(fmaxf(st4[0][q], st4[1][q]), fmaxf(st4[2][q], st4[3][q]));
#pragma unroll
      for (int off = 1; off < 16; off <<= 1)
#pragma unroll
        for (int q = 0; q < 4; ++q) mx[q] = fmaxf(mx[q], __shfl_xor(mx[q], off));
      int anyup = 0;
#pragma unroll
      for (int q = 0; q < 4; ++q) {
        const int up = mx[q] > m[q] + 8.f;
        anyup |= up;
        const float mn = up ? mx[q] : m[q];
        al[q] = up ? __expf(m[q] - mn) : 1.f;
        m[q] = mn;
      }
#pragma unroll
      for (int stt = 0; stt < 4; ++stt)
#pragma unroll
        for (int q = 0; q < 4; ++q) st4[stt][q] = __expf(st4[stt][q] - m[q]);
#pragma unroll
      for (int q = 0; q < 4; ++q)
        ps4[q] = (st4[0][q] + st4[1][q]) + (st4[2][q] + st4[3][q]);
#pragma unroll
      for (int off = 1; off < 16; off <<= 1)
#pragma unroll
        for (int q = 0; q < 4; ++q) ps4[q] += __shfl_xor(ps4[q], off);
#pragma unroll
      for (int q = 0; q < 4; ++q) s[q] = s[q] * al[q] + ps4[q];
      if (__any(anyup)) {
#pragma unroll
        for (int nn = 0; nn < 8; ++nn)
#pragma unroll
          for (int q = 0; q < 4; ++q) o[nn][q] *= al[q];
      }
#pragma unroll
      for (int stt = 0; stt < 4; ++stt)
#pragma unroll
        for (int q = 0; q < 4; ++q) {
          const int rw = 4 * g + q;
          Pb[rw * 64 + ((stt * 16 + r) ^ ((rw & 7) << 3))] = (bf16)st4[stt][q];
        }
      bf16x8 pf[2];
#pragma unroll
      for (int kk = 0; kk < 2; ++kk)
        pf[kk] = *(const bf16x8*)(Pb + r * 64 + (((kk * 4 + g) ^ (r & 7)) * 8));
      __builtin_amdgcn_s_setprio(1);
#pragma unroll
      for (int nn = 0; nn < 8; ++nn) {
        const int d = nn * 16 + r;
#pragma unroll
        for (int kk = 0; kk < 2; ++kk) {
          const bf16x8 vf = *(const bf16x8*)(Vb + d * 64 + (((kk * 4 + g) ^ (r & 7)) * 8));
          o[nn] = __builtin_amdgcn_mfma_f32_16x16x32_bf16(pf[kk], vf, o[nn], 0, 0, 0);
        }
      }
      __builtin_amdgcn_s_setprio(0);
      __syncthreads();
      cur ^= 1;
    }
  }
  const long part = (long)(h * 64 + qt) * 2 + c;
  float* pob = po + part * 8192;
  const int row0 = w * 16 + 4 * g;
#pragma unroll
  for (int nn = 0; nn < 8; ++nn)
#pragma unroll
    for (int q = 0; q < 4; ++q)
      pob[(row0 + q) * 128 + nn * 16 + r] = o[nn][q];
  if (r == 0) {
#pragma unroll
    for (int q = 0; q < 4; ++q) {
      pm[part * 64 + row0 + q] = m[q];
      ps[part * 64 + row0 + q] = s[q];
    }
  }
}

// Merge the 2 KV-chunk partials per (qt, h) -> yb (bf16, [t][h*D+d]).
__global__ __launch_bounds__(256) void attn_reduce(const float* __restrict__ po,
                                                   const float* __restrict__ pm,
                                                   const float* __restrict__ ps,
                                                   bf16* __restrict__ yb) {
  const int qt = blockIdx.x, h = blockIdx.y;
  const int tid = threadIdx.x;
  const int row = tid >> 2, seg = (tid & 3) * 32;
  const int base = (h * 64 + qt) * 2;
  const float m0 = pm[(long)base * 64 + row], m1 = pm[(long)(base + 1) * 64 + row];
  const float s0 = ps[(long)base * 64 + row], s1 = ps[(long)(base + 1) * 64 + row];
  const float mm = fmaxf(m0, m1);
  const float e0 = __expf(m0 - mm), e1 = __expf(m1 - mm);
  const float ss = s0 * e0 + s1 * e1;
  const float a0 = e0 / ss, a1 = e1 / ss;
  const float* r0 = po + (long)base * 8192 + row * 128 + seg;
  const float* r1 = r0 + 8192;
  bf16 outv[32];
#pragma unroll
  for (int j = 0; j < 32; j += 4) {
    const float4 x0 = *(const float4*)(r0 + j);
    const float4 x1 = *(const float4*)(r1 + j);
    outv[j]     = (bf16)(a0 * x0.x + a1 * x1.x);
    outv[j + 1] = (bf16)(a0 * x0.y + a1 * x1.y);
    outv[j + 2] = (bf16)(a0 * x0.z + a1 * x1.z);
    outv[j + 3] = (bf16)(a0 * x0.w + a1 * x1.w);
  }
  bf16* dst = yb + (long)(qt * 64 + row) * DIM + h * D + seg;
#pragma unroll
  for (int cc = 0; cc < 4; ++cc)
    *(int4*)(dst + cc * 8) = *(const int4*)&outv[cc * 8];
}

extern "C" void kernel_launch(void* const* d_in, const int* in_sizes, int n_in,
                              void* d_out, int out_size, void* d_ws, size_t ws_size,
                              hipStream_t stream) {
  const float* x     = (const float*)d_in[0];
  const float* ve    = (const float*)d_in[1];
  const float* qkv_w = (const float*)d_in[2];
  const float* lam   = (const float*)d_in[3];
  const float* cproj = (const float*)d_in[4];
  float* out = (float*)d_out;

  // Region A (consumed before attn; aliased by po/pm/ps):
  bf16* qkv = (bf16*)d_ws;                 // T*N3
  bf16* xb  = qkv + (long)T * N3;          // T*DIM
  bf16* wb  = xb + (long)T * DIM;          // N3*DIM
  // Region B (live across attn):
  bf16* cb  = wb + (long)N3 * DIM;         // DIM*DIM
  bf16* qb  = cb + (long)DIM * DIM;        // H*T*D
  bf16* kb  = qb + (long)H * T * D;
  bf16* vt  = kb + (long)H * T * D;        // (h, d, t)
  bf16* yb  = vt + (long)H * T * D;        // T*DIM
  // Partials alias region A (qkv/xb/wb are dead by the time attn runs):
  float* po = (float*)d_ws;                // NPART * 8192
  float* pm = po + (long)NPART * 8192;     // NPART * 64
  float* ps = pm + (long)NPART * 64;       // NPART * 64

  cvt<<<dim3(T * DIM / 8 / 256), 256, 0, stream>>>(x, xb, T * DIM);
  cvt<<<dim3(N3 * DIM / 8 / 256), 256, 0, stream>>>(qkv_w, wb, N3 * DIM);
  cvt<<<dim3(DIM * DIM / 8 / 256), 256, 0, stream>>>(cproj, cb, DIM * DIM);

  gemm_bt<bf16><<<dim3(N3 / 128, T / 128), 256, 0, stream>>>(xb, wb, qkv, T, N3, DIM);
  qkv_post<<<dim3(T * H / 4), 256, 0, stream>>>(qkv, qb, kb);
  v_trans<<<dim3(T / 64, H), 256, 0, stream>>>(qkv, ve, lam, vt);
  attn<<<dim3(64 * 2 * H), 256, 0, stream>>>(qb, kb, vt, po, pm, ps);
  attn_reduce<<<dim3(64, H), 256, 0, stream>>>(po, pm, ps, yb);
  gemm_bt<float><<<dim3(DIM / 128, T / 128), 256, 0, stream>>>(yb, cb, out, T, DIM, DIM);
}